// Round 2
// baseline (313.766 us; speedup 1.0000x reference)
//
#include <hip/hip_runtime.h>
#include <hip/hip_cooperative_groups.h>

namespace cg = cooperative_groups;

typedef _Float16 half8 __attribute__((ext_vector_type(8)));
typedef float f32x4 __attribute__((ext_vector_type(4)));
typedef float f32x16 __attribute__((ext_vector_type(16)));
typedef unsigned int u32x4 __attribute__((ext_vector_type(4)));

#define NPTS 1024
#define NB 8
#define HDIM 512
#define CH 16
#define RT 1088              // 17*64 rows: 1024 pts + x row (1024) + zero pad

// workspace byte offsets
#define OFF_WBF 0u                         // 8*64*512 octets * 16B = 4 MB
#define OFF_A0F (4u*1024u*1024u)
#define A0SZ    (64u*RT*16u)               // 1,114,112
#define OFF_WLF (OFF_A0F + A0SZ)
#define OFF_FS  (OFF_WLF + 16384u)
#define OFF_PP  (OFF_FS + 65536u)
#define PPSZ    (32u*RT*16u*4u)            // 2,228,224
#define OFF_IS  (OFF_PP + PPSZ)
#define OFF_BX  (OFF_IS + 64u)

__device__ __forceinline__ float elu(float z) { return z > 0.f ? z : expm1f(z); }

__device__ __forceinline__ void gl16(const void* g, void* l) {
  __builtin_amdgcn_global_load_lds(
      (const __attribute__((address_space(1))) unsigned int*)g,
      (__attribute__((address_space(3))) unsigned int*)l, 16, 0, 0);
}

// ---- phase bodies shared by fused + fallback kernels ----

__device__ __forceinline__ void prep_job(int b, int t, float* sm,
    const float* __restrict__ s, const float* __restrict__ x,
    const float* __restrict__ Wfirst, const float* __restrict__ bfirst,
    const float* __restrict__ Wb, const float* __restrict__ Wlast,
    const float* __restrict__ Wf, const float* __restrict__ bf,
    _Float16* __restrict__ Wbf, _Float16* __restrict__ Wlf,
    _Float16* __restrict__ a0f, float* __restrict__ f_s,
    float* __restrict__ Isum) {
  if (b < 1024) {
    int i = b >> 7, koct = (b >> 1) & 63, n = (b & 1) * 256 + t;
    const float* src = Wb + ((size_t)i * 512 + koct * 8) * 512 + n;
    float v[8];
#pragma unroll
    for (int j = 0; j < 8; ++j) v[j] = src[j * 512];
    union { _Float16 h[8]; u32x4 u; } hu;
#pragma unroll
    for (int j = 0; j < 8; ++j) hu.h[j] = (_Float16)v[j];
    *(u32x4*)(Wbf + ((size_t)(i * 64 + koct) * 512 + n) * 8) = hu.u;
  } else if (b < 1296) {
    int rr = t >> 6, tl = t & 63;
    int m = (b - 1024) * 4 + rr;
    float* sv = &sm[rr * 8];
    if (tl < 8) sv[tl] = (m < 1024) ? s[m * 8 + tl] : (m == 1024 ? x[tl] : 0.f);
    __syncthreads();
    size_t o = ((size_t)tl * RT + m) * 8;
    if (m <= 1024) {
      float acc[8];
#pragma unroll
      for (int jj = 0; jj < 8; ++jj) acc[jj] = bfirst[8 * tl + jj];
#pragma unroll
      for (int d = 0; d < 8; ++d) {
        float sd = sv[d];
        f32x4 w0 = *(const f32x4*)&Wfirst[d * 512 + 8 * tl];
        f32x4 w1 = *(const f32x4*)&Wfirst[d * 512 + 8 * tl + 4];
#pragma unroll
        for (int e = 0; e < 4; ++e) { acc[e] += sd * w0[e]; acc[4 + e] += sd * w1[e]; }
      }
      union { _Float16 h[8]; u32x4 u; } hu;
#pragma unroll
      for (int jj = 0; jj < 8; ++jj) hu.h[jj] = (_Float16)elu(acc[jj]);
      *(u32x4*)(a0f + o) = hu.u;
      if (m < 1024 && tl < 16) {
        float a = bf[tl];
#pragma unroll
        for (int d = 0; d < 8; ++d) a += sv[d] * Wf[d * 16 + tl];
        f_s[m * 16 + tl] = a;
      }
    } else {
      u32x4 z;
#pragma unroll
      for (int e = 0; e < 4; ++e) z[e] = 0u;
      *(u32x4*)(a0f + o) = z;
    }
  } else {
    if (t < 8) Isum[t] = 0.f;
#pragma unroll
    for (int it = 0; it < 32; ++it) sm[t + 256 * it] = Wlast[t + 256 * it];
    __syncthreads();
#pragma unroll
    for (int p = 0; p < 4; ++p) {
      int oi = p * 256 + t;
      int ko = oi >> 4, ch = oi & 15;
      union { _Float16 h[8]; u32x4 u; } hu;
#pragma unroll
      for (int jj = 0; jj < 8; ++jj) hu.h[jj] = (_Float16)sm[(ko * 8 + jj) * 16 + ch];
      *(u32x4*)(Wlf + oi * 8) = hu.u;
    }
  }
}

// ---- kB phase: LDS-staged double-buffered MFMA GEMM (m97-style) ----
// job b in [0,544) = i(8, ==XCD) x mt(17) x nq(4). Block: 64m x 128n, BK=64, 4 waves.
// LDS: A dbuf 2x8KB | B dbuf 2x16KB = 48KB.

#define STAGE(buf, ks) do {                                                          \
    int kb_ = (ks) * 8;                                                              \
    char* lA_ = lds + (buf) * 8192;                                                  \
    char* lB_ = lds + 16384 + (buf) * 16384;                                         \
    gl16(&a4[(size_t)(kb_ + (t >> 6)) * RT + m0 + (t & 63)], lA_ + t * 16);          \
    gl16(&a4[(size_t)(kb_ + 4 + (t >> 6)) * RT + m0 + (t & 63)], lA_ + 4096 + t * 16); \
    gl16(&b4[(size_t)(ib + kb_ + (t >> 7)) * 512 + n0 + (t & 127)], lB_ + t * 16);   \
    gl16(&b4[(size_t)(ib + kb_ + 2 + (t >> 7)) * 512 + n0 + (t & 127)], lB_ + 4096 + t * 16); \
    gl16(&b4[(size_t)(ib + kb_ + 4 + (t >> 7)) * 512 + n0 + (t & 127)], lB_ + 8192 + t * 16); \
    gl16(&b4[(size_t)(ib + kb_ + 6 + (t >> 7)) * 512 + n0 + (t & 127)], lB_ + 12288 + t * 16); \
  } while (0)

#define COMP(buf) do {                                                               \
    const u32x4* Ab_ = (const u32x4*)(lds + (buf) * 8192);                           \
    const u32x4* Bb_ = (const u32x4*)(lds + 16384 + (buf) * 16384);                  \
    _Pragma("unroll")                                                                \
    for (int kk = 0; kk < 4; ++kk) {                                                 \
      int ko_ = 2 * kk + q;                                                          \
      u32x4 av = Ab_[ko_ * 64 + wr * 32 + ln];                                       \
      u32x4 bv0 = Bb_[ko_ * 128 + nc + ln];                                          \
      u32x4 bv1 = Bb_[ko_ * 128 + nc + 32 + ln];                                     \
      acc0 = __builtin_amdgcn_mfma_f32_32x32x16_f16(                                 \
          __builtin_bit_cast(half8, av), __builtin_bit_cast(half8, bv0), acc0, 0, 0, 0); \
      acc1 = __builtin_amdgcn_mfma_f32_32x32x16_f16(                                 \
          __builtin_bit_cast(half8, av), __builtin_bit_cast(half8, bv1), acc1, 0, 0, 0); \
    }                                                                                \
  } while (0)

__device__ __forceinline__ void gemm_job(int b, int t, char* lds,
    const _Float16* __restrict__ Wbf, const _Float16* __restrict__ a0f,
    const _Float16* __restrict__ Wlf, const float* __restrict__ bb,
    float* __restrict__ Pp) {
  int i = b & 7, r = b >> 3;
  int nq = r & 3, mt = r >> 2;
  int m0 = mt * 64, n0 = nq * 128;
  int w = t >> 6, lane = t & 63, ln = lane & 31, q = lane >> 5;
  int wr = w & 1, nc = (w >> 1) * 64;
  int ib = i * 64;
  const u32x4* a4 = (const u32x4*)a0f;
  const u32x4* b4 = (const u32x4*)Wbf;

  f32x16 acc0, acc1;
#pragma unroll
  for (int rr = 0; rr < 16; ++rr) { acc0[rr] = 0.f; acc1[rr] = 0.f; }

  STAGE(0, 0);
  __syncthreads();
#pragma unroll
  for (int st = 0; st < 8; ++st) {
    if (st < 7) STAGE((st + 1) & 1, st + 1);   // issue next-tile loads first (T3)
    COMP(st & 1);
    __syncthreads();                            // drains vmcnt -> next buf ready
  }

  // epilogue: bias + elu -> f16 A-frags in per-wave scratch, project with Wlast
  float* S2f = (float*)(lds + 16384);
#pragma unroll
  for (int z = 0; z < 4; ++z) S2f[t + 256 * z] = 0.f;

  _Float16* scr = (_Float16*)(lds + w * 4096);
  float bcA = bb[(size_t)i * 512 + n0 + nc + ln];
  float bcB = bb[(size_t)i * 512 + n0 + nc + 32 + ln];
#pragma unroll
  for (int rr = 0; rr < 16; ++rr) {
    int row = (rr & 3) + 8 * (rr >> 2) + 4 * q;   // 32x32 C-layout row
    float aA = elu(acc0[rr] + bcA);
    float aB = elu(acc1[rr] + bcB);
    int mt2 = row >> 4, m16 = row & 15;
    scr[(mt2 * 128 + (ln >> 3) * 16 + m16) * 8 + (ln & 7)] = (_Float16)aA;
    scr[(mt2 * 128 + (4 + (ln >> 3)) * 16 + m16) * 8 + (ln & 7)] = (_Float16)aB;
  }
  __syncthreads();

  const u32x4* s4 = (const u32x4*)(lds + w * 4096);
  const u32x4* w4 = (const u32x4*)Wlf;
  int ch = lane & 15, q4 = lane >> 4;
  int hb = (n0 + nc) >> 3;
  half8 wv0 = __builtin_bit_cast(half8, w4[(size_t)(hb + q4) * 16 + ch]);
  half8 wv1 = __builtin_bit_cast(half8, w4[(size_t)(hb + 4 + q4) * 16 + ch]);
#pragma unroll
  for (int mt2 = 0; mt2 < 2; ++mt2) {
    f32x4 D;
#pragma unroll
    for (int rr = 0; rr < 4; ++rr) D[rr] = 0.f;
    half8 p0 = __builtin_bit_cast(half8, s4[mt2 * 128 + q4 * 16 + ch]);
    half8 p1 = __builtin_bit_cast(half8, s4[mt2 * 128 + (4 + q4) * 16 + ch]);
    D = __builtin_amdgcn_mfma_f32_16x16x32_f16(p0, wv0, D, 0, 0, 0);
    D = __builtin_amdgcn_mfma_f32_16x16x32_f16(p1, wv1, D, 0, 0, 0);
#pragma unroll
    for (int rr = 0; rr < 4; ++rr)
      atomicAdd(&S2f[(wr * 32 + mt2 * 16 + q4 * 4 + rr) * 16 + ch], D[rr]);
  }
  __syncthreads();
  for (int o = t; o < 1024; o += 256) {
    int m = o >> 4, c2 = o & 15;
    Pp[((size_t)(i * 4 + nq) * RT + m0 + m) * 16 + c2] = S2f[m * 16 + c2];
  }
}

__device__ __forceinline__ void red_job(int b, int t, float* wsum,
    const float* __restrict__ Pp, const float* __restrict__ f_s,
    const float* __restrict__ blast, float* __restrict__ Isum,
    float* __restrict__ basisx) {
  int i = b / 33, mt = b - i * 33;
  const float* P0 = Pp + (size_t)(i * 4) * RT * 16;
  const size_t PS = (size_t)RT * 16;
  if (mt == 32) {
    if (t < 16) {
      size_t o = (size_t)1024 * 16 + t;
      basisx[i * 16 + t] = P0[o] + P0[PS + o] + P0[2 * PS + o] + P0[3 * PS + o] + blast[t];
    }
    return;
  }
  float loc = 0.f;
#pragma unroll
  for (int p = 0; p < 2; ++p) {
    int item = t + p * 256;
    int m = mt * 32 + (item >> 4), ch = item & 15;
    size_t o = (size_t)m * 16 + ch;
    float bs = P0[o] + P0[PS + o] + P0[2 * PS + o] + P0[3 * PS + o] + blast[ch];
    float d = f_s[o] - bs;
    loc += d * d;
  }
  loc += __shfl_xor(loc, 1, 64);
  loc += __shfl_xor(loc, 2, 64);
  loc += __shfl_xor(loc, 4, 64);
  loc += __shfl_xor(loc, 8, 64);
  loc += __shfl_xor(loc, 16, 64);
  loc += __shfl_xor(loc, 32, 64);
  int lane = t & 63, w = t >> 6;
  if (lane == 0) wsum[w] = loc;
  __syncthreads();
  if (t == 0) atomicAdd(&Isum[i], wsum[0] + wsum[1] + wsum[2] + wsum[3]);
}

__device__ __forceinline__ void fin_job(int t, float* muL,
    const float* __restrict__ Isum, const float* __restrict__ basisx,
    float* __restrict__ out) {
  if (t < 8) {
    float nb = 0.5f * sqrtf(Isum[t]);   // sqrt(VOLUME/NPTS * S) = sqrt(S/4)
    muL[t] = (nb <= 1000.0f) ? nb : 0.f;
  }
  __syncthreads();
  if (t < 128) {
    int ch = t & 15;
    float num = 0.f, den = 1e-7f;
#pragma unroll
    for (int i = 0; i < NB; ++i) {
      num += muL[i] * basisx[i * 16 + ch];
      den += muL[i];
    }
    out[t] = num / den;
  }
}

// ---------- fused cooperative kernel: grid 544 x 256, all four phases ----------
__global__ __launch_bounds__(256, 3) void kFused(
    const float* __restrict__ s, const float* __restrict__ x,
    const float* __restrict__ Wfirst, const float* __restrict__ bfirst,
    const float* __restrict__ Wb, const float* __restrict__ bb,
    const float* __restrict__ Wlast, const float* __restrict__ blast,
    const float* __restrict__ Wf, const float* __restrict__ bf,
    _Float16* __restrict__ Wbf, _Float16* __restrict__ Wlf,
    _Float16* __restrict__ a0f, float* __restrict__ f_s, float* __restrict__ Pp,
    float* __restrict__ Isum, float* __restrict__ basisx, float* __restrict__ out) {
  __shared__ __align__(16) char lds[49152];
  cg::grid_group grid = cg::this_grid();
  int t = threadIdx.x;

  // phase 1: prep (1297 jobs, grid-stride over 544 blocks)
  for (int job = blockIdx.x; job < 1297; job += 544) {
    prep_job(job, t, (float*)lds, s, x, Wfirst, bfirst, Wb, Wlast, Wf, bf,
             Wbf, Wlf, a0f, f_s, Isum);
    __syncthreads();
  }
  grid.sync();

  // phase 2: GEMM + project (exactly 544 jobs)
  gemm_job(blockIdx.x, t, lds, Wbf, a0f, Wlf, bb, Pp);
  grid.sync();

  // phase 3: diff^2 reduction (264 jobs)
  if (blockIdx.x < 264)
    red_job(blockIdx.x, t, (float*)lds, Pp, f_s, blast, Isum, basisx);
  grid.sync();

  // phase 4: mu + combine (block 0)
  if (blockIdx.x == 0) fin_job(t, (float*)lds, Isum, basisx, out);
}

// ---------- fallback standalone kernels (if cooperative capture unsupported) ----------
__global__ __launch_bounds__(256) void kPrep(const float* __restrict__ s,
    const float* __restrict__ x, const float* __restrict__ Wfirst,
    const float* __restrict__ bfirst, const float* __restrict__ Wb,
    const float* __restrict__ Wlast, const float* __restrict__ Wf,
    const float* __restrict__ bf,
    _Float16* __restrict__ Wbf, _Float16* __restrict__ Wlf,
    _Float16* __restrict__ a0f, float* __restrict__ f_s,
    float* __restrict__ Isum) {
  __shared__ __align__(16) float sm[8192];
  prep_job(blockIdx.x, threadIdx.x, sm, s, x, Wfirst, bfirst, Wb, Wlast, Wf, bf,
           Wbf, Wlf, a0f, f_s, Isum);
}

__global__ __launch_bounds__(256, 3) void kB(const _Float16* __restrict__ Wbf,
    const _Float16* __restrict__ a0f, const _Float16* __restrict__ Wlf,
    const float* __restrict__ bb, float* __restrict__ Pp) {
  __shared__ __align__(16) char lds[49152];
  gemm_job(blockIdx.x, threadIdx.x, lds, Wbf, a0f, Wlf, bb, Pp);
}

__global__ __launch_bounds__(256) void kRed(const float* __restrict__ Pp,
    const float* __restrict__ f_s, const float* __restrict__ blast,
    float* __restrict__ Isum, float* __restrict__ basisx) {
  __shared__ float wsum[4];
  red_job(blockIdx.x, threadIdx.x, wsum, Pp, f_s, blast, Isum, basisx);
}

__global__ __launch_bounds__(128) void kFin(const float* __restrict__ Isum,
    const float* __restrict__ basisx, float* __restrict__ out) {
  __shared__ float muL[8];
  fin_job(threadIdx.x, muL, Isum, basisx, out);
}

extern "C" void kernel_launch(void* const* d_in, const int* in_sizes, int n_in,
                              void* d_out, int out_size, void* d_ws, size_t ws_size,
                              hipStream_t stream) {
  const float* s      = (const float*)d_in[0];
  const float* x      = (const float*)d_in[1];
  const float* Wfirst = (const float*)d_in[2];
  const float* bfirst = (const float*)d_in[3];
  const float* Wb     = (const float*)d_in[4];
  const float* bb     = (const float*)d_in[5];
  const float* Wlast  = (const float*)d_in[6];
  const float* blast  = (const float*)d_in[7];
  const float* Wf     = (const float*)d_in[8];
  const float* bf     = (const float*)d_in[9];

  char* ws = (char*)d_ws;
  _Float16* Wbf = (_Float16*)(ws + OFF_WBF);
  _Float16* a0f = (_Float16*)(ws + OFF_A0F);
  _Float16* Wlf = (_Float16*)(ws + OFF_WLF);
  float* f_s    = (float*)(ws + OFF_FS);
  float* Pp     = (float*)(ws + OFF_PP);
  float* Isum   = (float*)(ws + OFF_IS);
  float* basisx = (float*)(ws + OFF_BX);
  float* out    = (float*)d_out;

  void* args[] = {&s, &x, &Wfirst, &bfirst, &Wb, &bb, &Wlast, &blast, &Wf, &bf,
                  &Wbf, &Wlf, &a0f, &f_s, &Pp, &Isum, &basisx, &out};
  hipError_t e = hipLaunchCooperativeKernel((const void*)kFused, dim3(544),
                                            dim3(256), args, 0, stream);
  if (e != hipSuccess) {
    // fallback: proven 4-dispatch path
    kPrep<<<1297, 256, 0, stream>>>(s, x, Wfirst, bfirst, Wb, Wlast, Wf, bf,
                                    Wbf, Wlf, a0f, f_s, Isum);
    kB<<<544, 256, 0, stream>>>(Wbf, a0f, Wlf, bb, Pp);
    kRed<<<264, 256, 0, stream>>>(Pp, f_s, blast, Isum, basisx);
    kFin<<<1, 128, 0, stream>>>(Isum, basisx, out);
  }
}

// Round 3
// 122.725 us; speedup vs baseline: 2.5567x; 2.5567x over previous
//
#include <hip/hip_runtime.h>

typedef _Float16 half8 __attribute__((ext_vector_type(8)));
typedef float f32x4 __attribute__((ext_vector_type(4)));
typedef float f32x16 __attribute__((ext_vector_type(16)));
typedef unsigned int u32x4 __attribute__((ext_vector_type(4)));

#define NPTS 1024
#define NB 8
#define HDIM 512
#define CH 16
#define RT 1088              // 17*64 rows: 1024 pts + x row (1024) + zero pad

// workspace byte offsets
#define OFF_WBF 0u                         // 8*64*512 octets * 16B = 4 MB
#define OFF_A0F (4u*1024u*1024u)
#define A0SZ    (64u*RT*16u)               // 1,114,112
#define OFF_WLF (OFF_A0F + A0SZ)
#define OFF_FS  (OFF_WLF + 16384u)
#define OFF_PP  (OFF_FS + 65536u)
#define PPSZ    (32u*RT*16u*4u)            // 2,228,224
#define OFF_IS  (OFF_PP + PPSZ)            // 8 floats Isum + 1 uint counter
#define OFF_BX  (OFF_IS + 64u)

__device__ __forceinline__ float elu(float z) { return z > 0.f ? z : expm1f(z); }

__device__ __forceinline__ void gl16(const void* g, void* l) {
  __builtin_amdgcn_global_load_lds(
      (const __attribute__((address_space(1))) unsigned int*)g,
      (__attribute__((address_space(3))) unsigned int*)l, 16, 0, 0);
}

// ---------- kPrep ----------
// blocks 0..1023   : Wb -> f16 octets [i*64+koct][n][8], 1 octet/thread
// blocks 1024..1295: a0 rows (4/block): elu(s@Wfirst+b) -> octets [koct][m][8]; f_s
// block 1296       : Wlast -> octets [hoct][ch][8]; zero Isum + done-counter
__global__ __launch_bounds__(256) void kPrep(const float* __restrict__ s,
    const float* __restrict__ x, const float* __restrict__ Wfirst,
    const float* __restrict__ bfirst, const float* __restrict__ Wb,
    const float* __restrict__ Wlast, const float* __restrict__ Wf,
    const float* __restrict__ bf,
    _Float16* __restrict__ Wbf, _Float16* __restrict__ Wlf,
    _Float16* __restrict__ a0f, float* __restrict__ f_s,
    float* __restrict__ Isum, unsigned* __restrict__ cnt) {
  __shared__ __align__(16) float sm[8192];
  int b = blockIdx.x, t = threadIdx.x;
  if (b < 1024) {
    int i = b >> 7, koct = (b >> 1) & 63, n = (b & 1) * 256 + t;
    const float* src = Wb + ((size_t)i * 512 + koct * 8) * 512 + n;
    float v[8];
#pragma unroll
    for (int j = 0; j < 8; ++j) v[j] = src[j * 512];
    union { _Float16 h[8]; u32x4 u; } hu;
#pragma unroll
    for (int j = 0; j < 8; ++j) hu.h[j] = (_Float16)v[j];
    *(u32x4*)(Wbf + ((size_t)(i * 64 + koct) * 512 + n) * 8) = hu.u;
  } else if (b < 1296) {
    int rr = t >> 6, tl = t & 63;
    int m = (b - 1024) * 4 + rr;
    float* sv = &sm[rr * 8];
    if (tl < 8) sv[tl] = (m < 1024) ? s[m * 8 + tl] : (m == 1024 ? x[tl] : 0.f);
    __syncthreads();
    size_t o = ((size_t)tl * RT + m) * 8;
    if (m <= 1024) {
      float acc[8];
#pragma unroll
      for (int jj = 0; jj < 8; ++jj) acc[jj] = bfirst[8 * tl + jj];
#pragma unroll
      for (int d = 0; d < 8; ++d) {
        float sd = sv[d];
        f32x4 w0 = *(const f32x4*)&Wfirst[d * 512 + 8 * tl];
        f32x4 w1 = *(const f32x4*)&Wfirst[d * 512 + 8 * tl + 4];
#pragma unroll
        for (int e = 0; e < 4; ++e) { acc[e] += sd * w0[e]; acc[4 + e] += sd * w1[e]; }
      }
      union { _Float16 h[8]; u32x4 u; } hu;
#pragma unroll
      for (int jj = 0; jj < 8; ++jj) hu.h[jj] = (_Float16)elu(acc[jj]);
      *(u32x4*)(a0f + o) = hu.u;
      if (m < 1024 && tl < 16) {
        float a = bf[tl];
#pragma unroll
        for (int d = 0; d < 8; ++d) a += sv[d] * Wf[d * 16 + tl];
        f_s[m * 16 + tl] = a;
      }
    } else {
      u32x4 z;
#pragma unroll
      for (int e = 0; e < 4; ++e) z[e] = 0u;
      *(u32x4*)(a0f + o) = z;
    }
  } else {
    if (t < 8) Isum[t] = 0.f;
    if (t == 8) *cnt = 0u;
#pragma unroll
    for (int it = 0; it < 32; ++it) sm[t + 256 * it] = Wlast[t + 256 * it];
    __syncthreads();
#pragma unroll
    for (int p = 0; p < 4; ++p) {
      int oi = p * 256 + t;
      int ko = oi >> 4, ch = oi & 15;
      union { _Float16 h[8]; u32x4 u; } hu;
#pragma unroll
      for (int jj = 0; jj < 8; ++jj) hu.h[jj] = (_Float16)sm[(ko * 8 + jj) * 16 + ch];
      *(u32x4*)(Wlf + oi * 8) = hu.u;
    }
  }
}

// ---------- kB: LDS-staged double-buffered MFMA GEMM (m97-style) ----------
// grid 544 = i(8, ==XCD) x mt(17) x nq(4). Block: 64m x 128n, BK=64, 4 waves.
// Wave (wr,wc): 32m x 64n -> 2 acc tiles. global_load_lds (16B) -> linear LDS.
// LDS: A dbuf 2x8KB | B dbuf 2x16KB = 48KB -> 3 blocks/CU co-residency.

#define STAGE(buf, ks) do {                                                          \
    int kb_ = (ks) * 8;                                                              \
    char* lA_ = lds + (buf) * 8192;                                                  \
    char* lB_ = lds + 16384 + (buf) * 16384;                                         \
    gl16(&a4[(size_t)(kb_ + (t >> 6)) * RT + m0 + (t & 63)], lA_ + t * 16);          \
    gl16(&a4[(size_t)(kb_ + 4 + (t >> 6)) * RT + m0 + (t & 63)], lA_ + 4096 + t * 16); \
    gl16(&b4[(size_t)(ib + kb_ + (t >> 7)) * 512 + n0 + (t & 127)], lB_ + t * 16);   \
    gl16(&b4[(size_t)(ib + kb_ + 2 + (t >> 7)) * 512 + n0 + (t & 127)], lB_ + 4096 + t * 16); \
    gl16(&b4[(size_t)(ib + kb_ + 4 + (t >> 7)) * 512 + n0 + (t & 127)], lB_ + 8192 + t * 16); \
    gl16(&b4[(size_t)(ib + kb_ + 6 + (t >> 7)) * 512 + n0 + (t & 127)], lB_ + 12288 + t * 16); \
  } while (0)

#define COMP(buf) do {                                                               \
    const u32x4* Ab_ = (const u32x4*)(lds + (buf) * 8192);                           \
    const u32x4* Bb_ = (const u32x4*)(lds + 16384 + (buf) * 16384);                  \
    _Pragma("unroll")                                                                \
    for (int kk = 0; kk < 4; ++kk) {                                                 \
      int ko_ = 2 * kk + q;                                                          \
      u32x4 av = Ab_[ko_ * 64 + wr * 32 + ln];                                       \
      u32x4 bv0 = Bb_[ko_ * 128 + nc + ln];                                          \
      u32x4 bv1 = Bb_[ko_ * 128 + nc + 32 + ln];                                     \
      acc0 = __builtin_amdgcn_mfma_f32_32x32x16_f16(                                 \
          __builtin_bit_cast(half8, av), __builtin_bit_cast(half8, bv0), acc0, 0, 0, 0); \
      acc1 = __builtin_amdgcn_mfma_f32_32x32x16_f16(                                 \
          __builtin_bit_cast(half8, av), __builtin_bit_cast(half8, bv1), acc1, 0, 0, 0); \
    }                                                                                \
  } while (0)

__global__ __launch_bounds__(256, 3) void kB(const _Float16* __restrict__ Wbf,
    const _Float16* __restrict__ a0f, const _Float16* __restrict__ Wlf,
    const float* __restrict__ bb, float* __restrict__ Pp) {
  __shared__ __align__(16) char lds[49152];
  int t = threadIdx.x, b = blockIdx.x;
  int i = b & 7, r = b >> 3;
  int nq = r & 3, mt = r >> 2;
  int m0 = mt * 64, n0 = nq * 128;
  int w = t >> 6, lane = t & 63, ln = lane & 31, q = lane >> 5;
  int wr = w & 1, nc = (w >> 1) * 64;
  int ib = i * 64;
  const u32x4* a4 = (const u32x4*)a0f;
  const u32x4* b4 = (const u32x4*)Wbf;

  f32x16 acc0, acc1;
#pragma unroll
  for (int rr = 0; rr < 16; ++rr) { acc0[rr] = 0.f; acc1[rr] = 0.f; }

  STAGE(0, 0);
  __syncthreads();
#pragma unroll
  for (int st = 0; st < 8; ++st) {
    if (st < 7) STAGE((st + 1) & 1, st + 1);   // issue next-tile loads first (T3)
    COMP(st & 1);
    __syncthreads();                            // drains vmcnt -> next buf ready
  }

  // ---- epilogue: bias + elu -> f16 A-frags in per-wave scratch, project with Wlast ----
  float* S2f = (float*)(lds + 16384);            // [64][16] f32, reuses B buf0 region
#pragma unroll
  for (int z = 0; z < 4; ++z) S2f[t + 256 * z] = 0.f;

  _Float16* scr = (_Float16*)(lds + w * 4096);   // per-wave 4KB, reuses A region
  float bcA = bb[(size_t)i * 512 + n0 + nc + ln];
  float bcB = bb[(size_t)i * 512 + n0 + nc + 32 + ln];
#pragma unroll
  for (int rr = 0; rr < 16; ++rr) {
    int row = (rr & 3) + 8 * (rr >> 2) + 4 * q;   // 32x32 C-layout row
    float aA = elu(acc0[rr] + bcA);
    float aB = elu(acc1[rr] + bcB);
    int mt2 = row >> 4, m16 = row & 15;
    scr[(mt2 * 128 + (ln >> 3) * 16 + m16) * 8 + (ln & 7)] = (_Float16)aA;
    scr[(mt2 * 128 + (4 + (ln >> 3)) * 16 + m16) * 8 + (ln & 7)] = (_Float16)aB;
  }
  __syncthreads();

  const u32x4* s4 = (const u32x4*)(lds + w * 4096);
  const u32x4* w4 = (const u32x4*)Wlf;
  int ch = lane & 15, q4 = lane >> 4;
  int hb = (n0 + nc) >> 3;
  half8 wv0 = __builtin_bit_cast(half8, w4[(size_t)(hb + q4) * 16 + ch]);
  half8 wv1 = __builtin_bit_cast(half8, w4[(size_t)(hb + 4 + q4) * 16 + ch]);
#pragma unroll
  for (int mt2 = 0; mt2 < 2; ++mt2) {
    f32x4 D;
#pragma unroll
    for (int rr = 0; rr < 4; ++rr) D[rr] = 0.f;
    half8 p0 = __builtin_bit_cast(half8, s4[mt2 * 128 + q4 * 16 + ch]);
    half8 p1 = __builtin_bit_cast(half8, s4[mt2 * 128 + (4 + q4) * 16 + ch]);
    D = __builtin_amdgcn_mfma_f32_16x16x32_f16(p0, wv0, D, 0, 0, 0);
    D = __builtin_amdgcn_mfma_f32_16x16x32_f16(p1, wv1, D, 0, 0, 0);
#pragma unroll
    for (int rr = 0; rr < 4; ++rr)
      atomicAdd(&S2f[(wr * 32 + mt2 * 16 + q4 * 4 + rr) * 16 + ch], D[rr]);
  }
  __syncthreads();
  for (int o = t; o < 1024; o += 256) {
    int m = o >> 4, c2 = o & 15;
    Pp[((size_t)(i * 4 + nq) * RT + m0 + m) * 16 + c2] = S2f[m * 16 + c2];
  }
}

// ---------- kRedFin: diff^2 reduction -> Isum atomics; last-done block finishes ----------
// grid 264 = i(8) x mt(33). mt<32: 32m x 16ch diff^2 -> one atomicAdd. mt==32: basisx.
// Completion: fence + atomicAdd(cnt); block receiving rank 263 computes mu + output.
__global__ __launch_bounds__(256) void kRedFin(const float* __restrict__ Pp,
    const float* __restrict__ f_s, const float* __restrict__ blast,
    float* __restrict__ Isum, float* __restrict__ basisx,
    unsigned* __restrict__ cnt, float* __restrict__ out) {
  __shared__ float wsum[4];
  __shared__ unsigned rank;
  __shared__ float muL[8];
  int b = blockIdx.x, t = threadIdx.x;
  int i = b / 33, mt = b - i * 33;
  const float* P0 = Pp + (size_t)(i * 4) * RT * 16;
  const size_t PS = (size_t)RT * 16;
  if (mt == 32) {
    if (t < 16) {
      size_t o = (size_t)1024 * 16 + t;
      basisx[i * 16 + t] = P0[o] + P0[PS + o] + P0[2 * PS + o] + P0[3 * PS + o] + blast[t];
    }
  } else {
    float loc = 0.f;
#pragma unroll
    for (int p = 0; p < 2; ++p) {
      int item = t + p * 256;
      int m = mt * 32 + (item >> 4), ch = item & 15;
      size_t o = (size_t)m * 16 + ch;
      float bs = P0[o] + P0[PS + o] + P0[2 * PS + o] + P0[3 * PS + o] + blast[ch];
      float d = f_s[o] - bs;
      loc += d * d;
    }
    loc += __shfl_xor(loc, 1, 64);
    loc += __shfl_xor(loc, 2, 64);
    loc += __shfl_xor(loc, 4, 64);
    loc += __shfl_xor(loc, 8, 64);
    loc += __shfl_xor(loc, 16, 64);
    loc += __shfl_xor(loc, 32, 64);
    int lane = t & 63, w = t >> 6;
    if (lane == 0) wsum[w] = loc;
    __syncthreads();
    if (t == 0) atomicAdd(&Isum[i], wsum[0] + wsum[1] + wsum[2] + wsum[3]);
  }

  // completion protocol (device-scope: Isum adds are atomics; basisx stores fenced)
  __threadfence();
  if (t == 0) rank = atomicAdd(cnt, 1u);
  __syncthreads();
  if (rank == 263) {
    __threadfence();
    if (t < 8) {
      float nb = 0.5f * sqrtf(Isum[t]);   // sqrt(VOLUME/NPTS * S) = sqrt(S/4)
      muL[t] = (nb <= 1000.0f) ? nb : 0.f;
    }
    __syncthreads();
    if (t < 128) {
      int ch = t & 15;
      float num = 0.f, den = 1e-7f;
#pragma unroll
      for (int ii = 0; ii < NB; ++ii) {
        num += muL[ii] * basisx[ii * 16 + ch];
        den += muL[ii];
      }
      out[t] = num / den;
    }
  }
}

extern "C" void kernel_launch(void* const* d_in, const int* in_sizes, int n_in,
                              void* d_out, int out_size, void* d_ws, size_t ws_size,
                              hipStream_t stream) {
  const float* s      = (const float*)d_in[0];
  const float* x      = (const float*)d_in[1];
  const float* Wfirst = (const float*)d_in[2];
  const float* bfirst = (const float*)d_in[3];
  const float* Wb     = (const float*)d_in[4];
  const float* bb     = (const float*)d_in[5];
  const float* Wlast  = (const float*)d_in[6];
  const float* blast  = (const float*)d_in[7];
  const float* Wf     = (const float*)d_in[8];
  const float* bf     = (const float*)d_in[9];

  char* ws = (char*)d_ws;
  _Float16* Wbf = (_Float16*)(ws + OFF_WBF);
  _Float16* a0f = (_Float16*)(ws + OFF_A0F);
  _Float16* Wlf = (_Float16*)(ws + OFF_WLF);
  float* f_s    = (float*)(ws + OFF_FS);
  float* Pp     = (float*)(ws + OFF_PP);
  float* Isum   = (float*)(ws + OFF_IS);
  unsigned* cnt = (unsigned*)(ws + OFF_IS + 32u);
  float* basisx = (float*)(ws + OFF_BX);
  float* out    = (float*)d_out;

  kPrep<<<1297, 256, 0, stream>>>(s, x, Wfirst, bfirst, Wb, Wlast, Wf, bf,
                                  Wbf, Wlf, a0f, f_s, Isum, cnt);
  kB<<<544, 256, 0, stream>>>(Wbf, a0f, Wlf, bb, Pp);
  kRedFin<<<264, 256, 0, stream>>>(Pp, f_s, blast, Isum, basisx, cnt, out);
}

// Round 4
// 109.577 us; speedup vs baseline: 2.8634x; 1.1200x over previous
//
#include <hip/hip_runtime.h>

typedef _Float16 half8 __attribute__((ext_vector_type(8)));
typedef float f32x4 __attribute__((ext_vector_type(4)));
typedef float f32x16 __attribute__((ext_vector_type(16)));
typedef unsigned int u32x4 __attribute__((ext_vector_type(4)));

#define NPTS 1024
#define NB 8
#define HDIM 512
#define CH 16
#define RT 1088              // 17*64 rows: 1024 pts + x row (1024) + zero pad

// workspace byte offsets
#define OFF_WBF 0u                         // 8*64*512 octets * 16B = 4 MB
#define OFF_A0F (4u*1024u*1024u)
#define A0SZ    (64u*RT*16u)               // 1,114,112
#define OFF_WLF (OFF_A0F + A0SZ)
#define OFF_FS  (OFF_WLF + 16384u)
#define OFF_PP  (OFF_FS + 65536u)
#define PPSZ    (32u*RT*16u*4u)            // 2,228,224
#define OFF_IS  (OFF_PP + PPSZ)
#define OFF_BX  (OFF_IS + 64u)

__device__ __forceinline__ float elu(float z) { return z > 0.f ? z : expm1f(z); }

__device__ __forceinline__ void gl16(const void* g, void* l) {
  __builtin_amdgcn_global_load_lds(
      (const __attribute__((address_space(1))) unsigned int*)g,
      (__attribute__((address_space(3))) unsigned int*)l, 16, 0, 0);
}

// ---------- kPrep ----------
// blocks 0..1023   : Wb -> f16 octets [i*64+koct][n][8], 1 octet/thread
// blocks 1024..1295: a0 rows (4/block): elu(s@Wfirst+b) -> octets [koct][m][8]; f_s
// block 1296       : Wlast -> octets [hoct][ch][8]; zero Isum
__global__ __launch_bounds__(256) void kPrep(const float* __restrict__ s,
    const float* __restrict__ x, const float* __restrict__ Wfirst,
    const float* __restrict__ bfirst, const float* __restrict__ Wb,
    const float* __restrict__ Wlast, const float* __restrict__ Wf,
    const float* __restrict__ bf,
    _Float16* __restrict__ Wbf, _Float16* __restrict__ Wlf,
    _Float16* __restrict__ a0f, float* __restrict__ f_s,
    float* __restrict__ Isum) {
  __shared__ __align__(16) float sm[8192];
  int b = blockIdx.x, t = threadIdx.x;
  if (b < 1024) {
    int i = b >> 7, koct = (b >> 1) & 63, n = (b & 1) * 256 + t;
    const float* src = Wb + ((size_t)i * 512 + koct * 8) * 512 + n;
    float v[8];
#pragma unroll
    for (int j = 0; j < 8; ++j) v[j] = src[j * 512];
    union { _Float16 h[8]; u32x4 u; } hu;
#pragma unroll
    for (int j = 0; j < 8; ++j) hu.h[j] = (_Float16)v[j];
    *(u32x4*)(Wbf + ((size_t)(i * 64 + koct) * 512 + n) * 8) = hu.u;
  } else if (b < 1296) {
    int rr = t >> 6, tl = t & 63;
    int m = (b - 1024) * 4 + rr;
    float* sv = &sm[rr * 8];
    if (tl < 8) sv[tl] = (m < 1024) ? s[m * 8 + tl] : (m == 1024 ? x[tl] : 0.f);
    __syncthreads();
    size_t o = ((size_t)tl * RT + m) * 8;
    if (m <= 1024) {
      float acc[8];
#pragma unroll
      for (int jj = 0; jj < 8; ++jj) acc[jj] = bfirst[8 * tl + jj];
#pragma unroll
      for (int d = 0; d < 8; ++d) {
        float sd = sv[d];
        f32x4 w0 = *(const f32x4*)&Wfirst[d * 512 + 8 * tl];
        f32x4 w1 = *(const f32x4*)&Wfirst[d * 512 + 8 * tl + 4];
#pragma unroll
        for (int e = 0; e < 4; ++e) { acc[e] += sd * w0[e]; acc[4 + e] += sd * w1[e]; }
      }
      union { _Float16 h[8]; u32x4 u; } hu;
#pragma unroll
      for (int jj = 0; jj < 8; ++jj) hu.h[jj] = (_Float16)elu(acc[jj]);
      *(u32x4*)(a0f + o) = hu.u;
      if (m < 1024 && tl < 16) {
        float a = bf[tl];
#pragma unroll
        for (int d = 0; d < 8; ++d) a += sv[d] * Wf[d * 16 + tl];
        f_s[m * 16 + tl] = a;
      }
    } else {
      u32x4 z;
#pragma unroll
      for (int e = 0; e < 4; ++e) z[e] = 0u;
      *(u32x4*)(a0f + o) = z;
    }
  } else {
    if (t < 8) Isum[t] = 0.f;
#pragma unroll
    for (int it = 0; it < 32; ++it) sm[t + 256 * it] = Wlast[t + 256 * it];
    __syncthreads();
#pragma unroll
    for (int p = 0; p < 4; ++p) {
      int oi = p * 256 + t;
      int ko = oi >> 4, ch = oi & 15;
      union { _Float16 h[8]; u32x4 u; } hu;
#pragma unroll
      for (int jj = 0; jj < 8; ++jj) hu.h[jj] = (_Float16)sm[(ko * 8 + jj) * 16 + ch];
      *(u32x4*)(Wlf + oi * 8) = hu.u;
    }
  }
}

// ---------- kB: LDS-staged double-buffered MFMA GEMM (m97-style) ----------
// grid 544 = i(8, ==XCD) x mt(17) x nq(4). Block: 64m x 128n, BK=64, 4 waves.
// Wave (wr,wc): 32m x 64n -> 2 acc tiles. global_load_lds (16B) -> linear LDS.
// LDS: A dbuf 2x8KB | B dbuf 2x16KB = 48KB -> 3 blocks/CU co-residency.

#define STAGE(buf, ks) do {                                                          \
    int kb_ = (ks) * 8;                                                              \
    char* lA_ = lds + (buf) * 8192;                                                  \
    char* lB_ = lds + 16384 + (buf) * 16384;                                         \
    gl16(&a4[(size_t)(kb_ + (t >> 6)) * RT + m0 + (t & 63)], lA_ + t * 16);          \
    gl16(&a4[(size_t)(kb_ + 4 + (t >> 6)) * RT + m0 + (t & 63)], lA_ + 4096 + t * 16); \
    gl16(&b4[(size_t)(ib + kb_ + (t >> 7)) * 512 + n0 + (t & 127)], lB_ + t * 16);   \
    gl16(&b4[(size_t)(ib + kb_ + 2 + (t >> 7)) * 512 + n0 + (t & 127)], lB_ + 4096 + t * 16); \
    gl16(&b4[(size_t)(ib + kb_ + 4 + (t >> 7)) * 512 + n0 + (t & 127)], lB_ + 8192 + t * 16); \
    gl16(&b4[(size_t)(ib + kb_ + 6 + (t >> 7)) * 512 + n0 + (t & 127)], lB_ + 12288 + t * 16); \
  } while (0)

#define COMP(buf) do {                                                               \
    const u32x4* Ab_ = (const u32x4*)(lds + (buf) * 8192);                           \
    const u32x4* Bb_ = (const u32x4*)(lds + 16384 + (buf) * 16384);                  \
    _Pragma("unroll")                                                                \
    for (int kk = 0; kk < 4; ++kk) {                                                 \
      int ko_ = 2 * kk + q;                                                          \
      u32x4 av = Ab_[ko_ * 64 + wr * 32 + ln];                                       \
      u32x4 bv0 = Bb_[ko_ * 128 + nc + ln];                                          \
      u32x4 bv1 = Bb_[ko_ * 128 + nc + 32 + ln];                                     \
      acc0 = __builtin_amdgcn_mfma_f32_32x32x16_f16(                                 \
          __builtin_bit_cast(half8, av), __builtin_bit_cast(half8, bv0), acc0, 0, 0, 0); \
      acc1 = __builtin_amdgcn_mfma_f32_32x32x16_f16(                                 \
          __builtin_bit_cast(half8, av), __builtin_bit_cast(half8, bv1), acc1, 0, 0, 0); \
    }                                                                                \
  } while (0)

__global__ __launch_bounds__(256, 3) void kB(const _Float16* __restrict__ Wbf,
    const _Float16* __restrict__ a0f, const _Float16* __restrict__ Wlf,
    const float* __restrict__ bb, float* __restrict__ Pp) {
  __shared__ __align__(16) char lds[49152];
  int t = threadIdx.x, b = blockIdx.x;
  int i = b & 7, r = b >> 3;
  int nq = r & 3, mt = r >> 2;
  int m0 = mt * 64, n0 = nq * 128;
  int w = t >> 6, lane = t & 63, ln = lane & 31, q = lane >> 5;
  int wr = w & 1, nc = (w >> 1) * 64;
  int ib = i * 64;
  const u32x4* a4 = (const u32x4*)a0f;
  const u32x4* b4 = (const u32x4*)Wbf;

  f32x16 acc0, acc1;
#pragma unroll
  for (int rr = 0; rr < 16; ++rr) { acc0[rr] = 0.f; acc1[rr] = 0.f; }

  STAGE(0, 0);
  __syncthreads();
#pragma unroll
  for (int st = 0; st < 8; ++st) {
    if (st < 7) STAGE((st + 1) & 1, st + 1);   // issue next-tile loads first (T3)
    COMP(st & 1);
    __syncthreads();                            // drains vmcnt -> next buf ready
  }

  // ---- epilogue: bias + elu -> f16 A-frags in per-wave scratch, project with Wlast ----
  float* S2f = (float*)(lds + 16384);            // [64][16] f32, reuses B buf0 region
#pragma unroll
  for (int z = 0; z < 4; ++z) S2f[t + 256 * z] = 0.f;

  _Float16* scr = (_Float16*)(lds + w * 4096);   // per-wave 4KB, reuses A region
  float bcA = bb[(size_t)i * 512 + n0 + nc + ln];
  float bcB = bb[(size_t)i * 512 + n0 + nc + 32 + ln];
#pragma unroll
  for (int rr = 0; rr < 16; ++rr) {
    int row = (rr & 3) + 8 * (rr >> 2) + 4 * q;   // 32x32 C-layout row
    float aA = elu(acc0[rr] + bcA);
    float aB = elu(acc1[rr] + bcB);
    int mt2 = row >> 4, m16 = row & 15;
    scr[(mt2 * 128 + (ln >> 3) * 16 + m16) * 8 + (ln & 7)] = (_Float16)aA;
    scr[(mt2 * 128 + (4 + (ln >> 3)) * 16 + m16) * 8 + (ln & 7)] = (_Float16)aB;
  }
  __syncthreads();

  const u32x4* s4 = (const u32x4*)(lds + w * 4096);
  const u32x4* w4 = (const u32x4*)Wlf;
  int ch = lane & 15, q4 = lane >> 4;
  int hb = (n0 + nc) >> 3;
  half8 wv0 = __builtin_bit_cast(half8, w4[(size_t)(hb + q4) * 16 + ch]);
  half8 wv1 = __builtin_bit_cast(half8, w4[(size_t)(hb + 4 + q4) * 16 + ch]);
#pragma unroll
  for (int mt2 = 0; mt2 < 2; ++mt2) {
    f32x4 D;
#pragma unroll
    for (int rr = 0; rr < 4; ++rr) D[rr] = 0.f;
    half8 p0 = __builtin_bit_cast(half8, s4[mt2 * 128 + q4 * 16 + ch]);
    half8 p1 = __builtin_bit_cast(half8, s4[mt2 * 128 + (4 + q4) * 16 + ch]);
    D = __builtin_amdgcn_mfma_f32_16x16x32_f16(p0, wv0, D, 0, 0, 0);
    D = __builtin_amdgcn_mfma_f32_16x16x32_f16(p1, wv1, D, 0, 0, 0);
#pragma unroll
    for (int rr = 0; rr < 4; ++rr)
      atomicAdd(&S2f[(wr * 32 + mt2 * 16 + q4 * 4 + rr) * 16 + ch], D[rr]);
  }
  __syncthreads();
  for (int o = t; o < 1024; o += 256) {
    int m = o >> 4, c2 = o & 15;
    Pp[((size_t)(i * 4 + nq) * RT + m0 + m) * 16 + c2] = S2f[m * 16 + c2];
  }
}

// ---------- kRed: parallel diff^2 reduction -> Isum[i] atomics; basisx from x-row ----------
// grid 264 = i(8) x mt(33). mt<32: 32m x 16ch diff^2 -> one atomicAdd. mt==32: basisx.
__global__ __launch_bounds__(256) void kRed(const float* __restrict__ Pp,
    const float* __restrict__ f_s, const float* __restrict__ blast,
    float* __restrict__ Isum, float* __restrict__ basisx) {
  __shared__ float wsum[4];
  int b = blockIdx.x, t = threadIdx.x;
  int i = b / 33, mt = b - i * 33;
  const float* P0 = Pp + (size_t)(i * 4) * RT * 16;
  const size_t PS = (size_t)RT * 16;
  if (mt == 32) {
    if (t < 16) {
      size_t o = (size_t)1024 * 16 + t;
      basisx[i * 16 + t] = P0[o] + P0[PS + o] + P0[2 * PS + o] + P0[3 * PS + o] + blast[t];
    }
    return;
  }
  float loc = 0.f;
#pragma unroll
  for (int p = 0; p < 2; ++p) {
    int item = t + p * 256;
    int m = mt * 32 + (item >> 4), ch = item & 15;
    size_t o = (size_t)m * 16 + ch;
    float bs = P0[o] + P0[PS + o] + P0[2 * PS + o] + P0[3 * PS + o] + blast[ch];
    float d = f_s[o] - bs;
    loc += d * d;
  }
  loc += __shfl_xor(loc, 1, 64);
  loc += __shfl_xor(loc, 2, 64);
  loc += __shfl_xor(loc, 4, 64);
  loc += __shfl_xor(loc, 8, 64);
  loc += __shfl_xor(loc, 16, 64);
  loc += __shfl_xor(loc, 32, 64);
  int lane = t & 63, w = t >> 6;
  if (lane == 0) wsum[w] = loc;
  __syncthreads();
  if (t == 0) atomicAdd(&Isum[i], wsum[0] + wsum[1] + wsum[2] + wsum[3]);
}

// ---------- kFin: mu from Isum + weighted combine ----------
__global__ __launch_bounds__(128) void kFin(const float* __restrict__ Isum,
    const float* __restrict__ basisx, float* __restrict__ out) {
  __shared__ float muL[8];
  int t = threadIdx.x;
  if (t < 8) {
    float nb = 0.5f * sqrtf(Isum[t]);   // sqrt(VOLUME/NPTS * S) = sqrt(S/4)
    muL[t] = (nb <= 1000.0f) ? nb : 0.f;
  }
  __syncthreads();
  int ch = t & 15;
  float num = 0.f, den = 1e-7f;
#pragma unroll
  for (int i = 0; i < NB; ++i) {
    num += muL[i] * basisx[i * 16 + ch];
    den += muL[i];
  }
  out[t] = num / den;
}

extern "C" void kernel_launch(void* const* d_in, const int* in_sizes, int n_in,
                              void* d_out, int out_size, void* d_ws, size_t ws_size,
                              hipStream_t stream) {
  const float* s      = (const float*)d_in[0];
  const float* x      = (const float*)d_in[1];
  const float* Wfirst = (const float*)d_in[2];
  const float* bfirst = (const float*)d_in[3];
  const float* Wb     = (const float*)d_in[4];
  const float* bb     = (const float*)d_in[5];
  const float* Wlast  = (const float*)d_in[6];
  const float* blast  = (const float*)d_in[7];
  const float* Wf     = (const float*)d_in[8];
  const float* bf     = (const float*)d_in[9];

  char* ws = (char*)d_ws;
  _Float16* Wbf = (_Float16*)(ws + OFF_WBF);
  _Float16* a0f = (_Float16*)(ws + OFF_A0F);
  _Float16* Wlf = (_Float16*)(ws + OFF_WLF);
  float* f_s    = (float*)(ws + OFF_FS);
  float* Pp     = (float*)(ws + OFF_PP);
  float* Isum   = (float*)(ws + OFF_IS);
  float* basisx = (float*)(ws + OFF_BX);
  float* out    = (float*)d_out;

  kPrep<<<1297, 256, 0, stream>>>(s, x, Wfirst, bfirst, Wb, Wlast, Wf, bf,
                                  Wbf, Wlf, a0f, f_s, Isum);
  kB<<<544, 256, 0, stream>>>(Wbf, a0f, Wlf, bb, Pp);
  kRed<<<264, 256, 0, stream>>>(Pp, f_s, blast, Isum, basisx);
  kFin<<<1, 128, 0, stream>>>(Isum, basisx, out);
}